// Round 1
// baseline (363.847 us; speedup 1.0000x reference)
//
#include <hip/hip_runtime.h>
#include <math.h>

// Problem constants
#define N_IMG 16
#define C_CH 3
#define H_DIM 512
#define W_DIM 512
#define HW (H_DIM * W_DIM)              // 262144
#define KS 7
#define PAD 3

// Tile config for local-variance kernel
#define TS 16
#define TILE (TS + 2 * PAD)             // 22

// ws layout:
//   [0, N_IMG*HW*4)                       : residual  (float, N x H x W)
//   [RES_BYTES, RES_BYTES + N_IMG*16)     : per-image {sum, sumsq} doubles
//   [RES_BYTES + N_IMG*16, +8)            : final accumulator double
#define RES_BYTES ((size_t)N_IMG * HW * sizeof(float))   // 16,777,216

// ---------------------------------------------------------------------------
// Kernel 1: residual = sum_c |t - p|, write to ws; per-image sum & sumsq
// One thread handles 4 consecutive pixels (float4). Blocks never straddle
// images (65536 float4 per image, 256 per block -> 256 blocks/image).
// ---------------------------------------------------------------------------
__global__ void k_residual(const float4* __restrict__ pred,
                           const float4* __restrict__ targ,
                           float4* __restrict__ resid,
                           double* __restrict__ acc) {
    const int tid = blockIdx.x * blockDim.x + threadIdx.x;   // 0..1048575
    const int plane4 = HW / 4;                                // 65536
    const int n   = tid >> 16;                                // / 65536
    const int hw4 = tid & 0xFFFF;

    const float4* p = pred + (size_t)n * C_CH * plane4 + hw4;
    const float4* t = targ + (size_t)n * C_CH * plane4 + hw4;

    float4 r = make_float4(0.f, 0.f, 0.f, 0.f);
#pragma unroll
    for (int c = 0; c < C_CH; ++c) {
        float4 a = p[c * plane4];
        float4 b = t[c * plane4];
        r.x += fabsf(b.x - a.x);
        r.y += fabsf(b.y - a.y);
        r.z += fabsf(b.z - a.z);
        r.w += fabsf(b.w - a.w);
    }
    resid[tid] = r;

    float s  = r.x + r.y + r.z + r.w;
    float ss = r.x * r.x + r.y * r.y + r.z * r.z + r.w * r.w;

    // wave-64 reduce
#pragma unroll
    for (int off = 32; off > 0; off >>= 1) {
        s  += __shfl_down(s,  off);
        ss += __shfl_down(ss, off);
    }
    __shared__ float sh_s[4], sh_ss[4];
    const int lane = threadIdx.x & 63;
    const int wave = threadIdx.x >> 6;
    if (lane == 0) { sh_s[wave] = s; sh_ss[wave] = ss; }
    __syncthreads();
    if (threadIdx.x == 0) {
        float S  = sh_s[0]  + sh_s[1]  + sh_s[2]  + sh_s[3];
        float SS = sh_ss[0] + sh_ss[1] + sh_ss[2] + sh_ss[3];
        atomicAdd(&acc[2 * n + 0], (double)S);
        atomicAdd(&acc[2 * n + 1], (double)SS);
    }
}

// ---------------------------------------------------------------------------
// Kernel 2: 7x7 local unbiased variance (reflect padding) * patch_w * resid,
// block-reduce, atomicAdd into final accumulator.
// ---------------------------------------------------------------------------
__global__ void k_localvar(const float* __restrict__ resid,
                           const double* __restrict__ acc,
                           double* __restrict__ final_acc) {
    __shared__ float tile[TILE][TILE + 1];   // +1 pad vs bank conflicts

    const int bx = blockIdx.x & 31;                 // W_DIM/TS = 32
    const int by = (blockIdx.x >> 5) & 31;          // H_DIM/TS = 32
    const int n  = blockIdx.x >> 10;

    const float* rp = resid + (size_t)n * HW;

    // cooperative halo load with reflect indexing (jnp 'reflect': no edge dup)
    for (int i = threadIdx.x; i < TILE * TILE; i += blockDim.x) {
        int ly = i / TILE, lx = i % TILE;
        int gy = by * TS - PAD + ly;
        int gx = bx * TS - PAD + lx;
        gy = (gy < 0) ? -gy : ((gy >= H_DIM) ? (2 * H_DIM - 2 - gy) : gy);
        gx = (gx < 0) ? -gx : ((gx >= W_DIM) ? (2 * W_DIM - 2 - gx) : gx);
        tile[ly][lx] = rp[gy * W_DIM + gx];
    }
    __syncthreads();

    const int tx = threadIdx.x & (TS - 1);
    const int ty = threadIdx.x / TS;

    float s = 0.f, ss = 0.f;
#pragma unroll
    for (int dy = 0; dy < KS; ++dy) {
#pragma unroll
        for (int dx = 0; dx < KS; ++dx) {
            float v = tile[ty + dy][tx + dx];
            s  += v;
            ss += v * v;
        }
    }
    const float pix_var = (ss - s * s * (1.0f / 49.0f)) * (1.0f / 48.0f);

    // per-image patch weight (var over HW elems, ddof=1)^0.2
    const double S  = acc[2 * n + 0];
    const double SS = acc[2 * n + 1];
    const double pvar = (SS - S * S / (double)HW) / (double)(HW - 1);
    const float pw = powf((float)pvar, 0.2f);

    const float center = tile[ty + PAD][tx + PAD];
    float contrib = pw * pix_var * center;

#pragma unroll
    for (int off = 32; off > 0; off >>= 1)
        contrib += __shfl_down(contrib, off);

    __shared__ float sh[4];
    const int lane = threadIdx.x & 63;
    const int wave = threadIdx.x >> 6;
    if (lane == 0) sh[wave] = contrib;
    __syncthreads();
    if (threadIdx.x == 0) {
        float tot = sh[0] + sh[1] + sh[2] + sh[3];
        atomicAdd(final_acc, (double)tot);
    }
}

// ---------------------------------------------------------------------------
// Kernel 3: finalize scalar
// ---------------------------------------------------------------------------
__global__ void k_finalize(const double* __restrict__ final_acc,
                           float* __restrict__ out) {
    const double total_elems = (double)N_IMG * C_CH * HW;   // 12,582,912
    out[0] = (float)(final_acc[0] / total_elems);
}

extern "C" void kernel_launch(void* const* d_in, const int* in_sizes, int n_in,
                              void* d_out, int out_size, void* d_ws, size_t ws_size,
                              hipStream_t stream) {
    const float4* pred = (const float4*)d_in[0];
    const float4* targ = (const float4*)d_in[1];

    char* ws = (char*)d_ws;
    float4* resid      = (float4*)ws;
    double* acc        = (double*)(ws + RES_BYTES);               // 16 * 2 doubles
    double* final_acc  = (double*)(ws + RES_BYTES + N_IMG * 2 * sizeof(double));
    float*  out        = (float*)d_out;

    // zero accumulators (re-poisoned 0xAA before every timed launch)
    hipMemsetAsync(acc, 0, (N_IMG * 2 + 1) * sizeof(double), stream);

    // Kernel 1: 16 * 65536 float4 elements, 256 threads/block
    {
        const int total_threads = N_IMG * (HW / 4);   // 1,048,576
        k_residual<<<total_threads / 256, 256, 0, stream>>>(pred, targ, resid, acc);
    }
    // Kernel 2: one block per 16x16 tile
    {
        const int blocks = N_IMG * (H_DIM / TS) * (W_DIM / TS);   // 16,384
        k_localvar<<<blocks, TS * TS, 0, stream>>>((const float*)resid, acc, final_acc);
    }
    k_finalize<<<1, 1, 0, stream>>>(final_acc, out);
}

// Round 2
// 144.729 us; speedup vs baseline: 2.5140x; 2.5140x over previous
//
#include <hip/hip_runtime.h>
#include <math.h>

// Problem constants
#define N_IMG 16
#define C_CH 3
#define H_DIM 512
#define W_DIM 512
#define HW (H_DIM * W_DIM)              // 262144
#define KS 7
#define PAD 3

// Fused-kernel tiling: 32x32 output tile per block, 3-halo each side.
#define TS 32
#define TILE (TS + 2 * PAD)             // 38
#define TSTRIDE 40                      // row stride in LDS floats (40%32=8; 4-row offset = 160 = 0 mod 32 -> 2-way = free)
#define TPB 256
#define TILES_PER_IMG ((H_DIM / TS) * (W_DIM / TS))   // 256
#define NBLOCKS (N_IMG * TILES_PER_IMG)               // 4096

// ws layout: three float arrays of per-block partials (no atomics anywhere)
//   pr  [NBLOCKS] : sum of residual over the block's interior pixels
//   pr2 [NBLOCKS] : sum of residual^2
//   pc  [NBLOCKS] : sum of pix_var * residual

// ---------------------------------------------------------------------------
// Fused kernel: residual (recomputed with halo from pred/target), 7x7 local
// unbiased variance via vertical register-sliding window (4 px/thread),
// per-block partial sums -> ws. No global atomics.
// ---------------------------------------------------------------------------
__global__ __launch_bounds__(TPB) void k_fused(const float* __restrict__ pred,
                                               const float* __restrict__ targ,
                                               float* __restrict__ pr,
                                               float* __restrict__ pr2,
                                               float* __restrict__ pc) {
    __shared__ float tile[TILE * TSTRIDE];

    const int bid = blockIdx.x;
    const int n   = bid >> 8;              // 256 tiles per image
    const int t   = bid & 255;
    const int by  = t >> 4;                // 16 tiles per dim
    const int bx  = t & 15;
    const int tid = threadIdx.x;

    const float* p = pred + (size_t)n * C_CH * HW;
    const float* q = targ + (size_t)n * C_CH * HW;

    // --- residual tile with reflect halo (jnp 'reflect': no edge dup) ---
    for (int i = tid; i < TILE * TILE; i += TPB) {
        const int ly = i / TILE;
        const int lx = i - ly * TILE;
        int gy = by * TS - PAD + ly;
        int gx = bx * TS - PAD + lx;
        gy = (gy < 0) ? -gy : ((gy >= H_DIM) ? (2 * H_DIM - 2 - gy) : gy);
        gx = (gx < 0) ? -gx : ((gx >= W_DIM) ? (2 * W_DIM - 2 - gx) : gx);
        const int off = gy * W_DIM + gx;
        const float r = fabsf(q[off] - p[off])
                      + fabsf(q[off + HW] - p[off + HW])
                      + fabsf(q[off + 2 * HW] - p[off + 2 * HW]);
        tile[ly * TSTRIDE + lx] = r;
    }
    __syncthreads();

    // --- 4 vertically-adjacent output pixels per thread ---
    const int tx  = tid & 31;              // output column 0..31
    const int ty0 = (tid >> 5) << 2;       // output rows ty0..ty0+3

    float colS[KS], colSS[KS];
#pragma unroll
    for (int j = 0; j < KS; ++j) {
        float s = 0.f, ss = 0.f;
#pragma unroll
        for (int dy = 0; dy < KS; ++dy) {
            const float v = tile[(ty0 + dy) * TSTRIDE + tx + j];
            s  += v;
            ss += v * v;
        }
        colS[j] = s; colSS[j] = ss;
    }

    float acc_r = 0.f, acc_r2 = 0.f, acc_c = 0.f;

#pragma unroll
    for (int k = 0; k < 4; ++k) {
        if (k > 0) {
            // slide window down one row: add row ty0+6+k, drop row ty0+k-1
#pragma unroll
            for (int j = 0; j < KS; ++j) {
                const float vn = tile[(ty0 + 6 + k) * TSTRIDE + tx + j];
                const float vo = tile[(ty0 + k - 1) * TSTRIDE + tx + j];
                colS[j]  += vn - vo;
                colSS[j] += vn * vn - vo * vo;
            }
        }
        float S = 0.f, SS = 0.f;
#pragma unroll
        for (int j = 0; j < KS; ++j) { S += colS[j]; SS += colSS[j]; }

        const float pix_var = (SS - S * S * (1.0f / 49.0f)) * (1.0f / 48.0f);
        const float center  = tile[(ty0 + 3 + k) * TSTRIDE + tx + 3];

        acc_r  += center;
        acc_r2 += center * center;
        acc_c  += pix_var * center;
    }

    // --- block reduce 3 floats (wave shuffle -> LDS -> thread 0) ---
#pragma unroll
    for (int off = 32; off > 0; off >>= 1) {
        acc_r  += __shfl_down(acc_r,  off);
        acc_r2 += __shfl_down(acc_r2, off);
        acc_c  += __shfl_down(acc_c,  off);
    }
    __shared__ float sh_r[4], sh_r2[4], sh_c[4];
    const int lane = tid & 63;
    const int wave = tid >> 6;
    if (lane == 0) { sh_r[wave] = acc_r; sh_r2[wave] = acc_r2; sh_c[wave] = acc_c; }
    __syncthreads();
    if (tid == 0) {
        pr [bid] = sh_r [0] + sh_r [1] + sh_r [2] + sh_r [3];
        pr2[bid] = sh_r2[0] + sh_r2[1] + sh_r2[2] + sh_r2[3];
        pc [bid] = sh_c [0] + sh_c [1] + sh_c [2] + sh_c [3];
    }
}

// ---------------------------------------------------------------------------
// Finalize: wave w reduces image w's 256 partials in double; lane 0 applies
// pw_n = pvar^0.2; thread 0 sums the 16 images and writes the scalar.
// ---------------------------------------------------------------------------
__global__ void k_final(const float* __restrict__ pr,
                        const float* __restrict__ pr2,
                        const float* __restrict__ pc,
                        float* __restrict__ out) {
    __shared__ double sh[N_IMG];
    const int tid  = threadIdx.x;       // 1024 threads = 16 waves
    const int w    = tid >> 6;          // image index
    const int lane = tid & 63;

    double R = 0.0, R2 = 0.0, Cs = 0.0;
    for (int i = lane; i < TILES_PER_IMG; i += 64) {
        const int idx = w * TILES_PER_IMG + i;
        R  += (double)pr[idx];
        R2 += (double)pr2[idx];
        Cs += (double)pc[idx];
    }
#pragma unroll
    for (int off = 32; off > 0; off >>= 1) {
        R  += __shfl_down(R,  off);
        R2 += __shfl_down(R2, off);
        Cs += __shfl_down(Cs, off);
    }
    if (lane == 0) {
        const double pvar = (R2 - R * R / (double)HW) / (double)(HW - 1);
        sh[w] = pow(pvar, 0.2) * Cs;
    }
    __syncthreads();
    if (tid == 0) {
        double s = 0.0;
        for (int i = 0; i < N_IMG; ++i) s += sh[i];
        out[0] = (float)(s / ((double)N_IMG * C_CH * HW));
    }
}

extern "C" void kernel_launch(void* const* d_in, const int* in_sizes, int n_in,
                              void* d_out, int out_size, void* d_ws, size_t ws_size,
                              hipStream_t stream) {
    const float* pred = (const float*)d_in[0];
    const float* targ = (const float*)d_in[1];

    float* pr  = (float*)d_ws;
    float* pr2 = pr  + NBLOCKS;
    float* pc  = pr2 + NBLOCKS;
    float* out = (float*)d_out;

    k_fused<<<NBLOCKS, TPB, 0, stream>>>(pred, targ, pr, pr2, pc);
    k_final<<<1, 1024, 0, stream>>>(pr, pr2, pc, out);
}

// Round 3
// 126.781 us; speedup vs baseline: 2.8699x; 1.1416x over previous
//
#include <hip/hip_runtime.h>
#include <math.h>

// Problem constants
#define N_IMG 16
#define C_CH 3
#define H_DIM 512
#define W_DIM 512
#define HW (H_DIM * W_DIM)              // 262144
#define KS 7
#define PAD 3

// Fused-kernel tiling: 64x64 output tile per block, 3-halo each side.
#define TS 64
#define TILE (TS + 2 * PAD)             // 70
#define TSTRIDE 72                      // LDS row stride (floats)
#define TPB 256
#define TILES_PER_IMG ((H_DIM / TS) * (W_DIM / TS))   // 64
#define NBLOCKS (N_IMG * TILES_PER_IMG)               // 1024

// ws layout: three float arrays of per-block partials (no atomics anywhere)
//   pr  [NBLOCKS] : sum of residual over the block's interior pixels
//   pr2 [NBLOCKS] : sum of residual^2
//   pc  [NBLOCKS] : sum of pix_var * residual

// ---------------------------------------------------------------------------
// Fused kernel: residual (recomputed with reflect halo from pred/target) into
// LDS, 7x7 local unbiased variance via ring-buffer row-sum sliding window
// (16 px/thread, O(1) LDS work per slide), per-block partials -> ws.
// ---------------------------------------------------------------------------
__global__ __launch_bounds__(TPB) void k_fused(const float* __restrict__ pred,
                                               const float* __restrict__ targ,
                                               float* __restrict__ pr,
                                               float* __restrict__ pr2,
                                               float* __restrict__ pc) {
    __shared__ float tile[TILE * TSTRIDE];

    const int bid = blockIdx.x;
    const int n   = bid >> 6;              // 64 tiles per image
    const int t   = bid & 63;
    const int by  = t >> 3;                // 8 tiles per dim
    const int bx  = t & 7;
    const int tid = threadIdx.x;

    const float* p0 = pred + (size_t)n * C_CH * HW;
    const float* p1 = p0 + HW;
    const float* p2 = p1 + HW;
    const float* q0 = targ + (size_t)n * C_CH * HW;
    const float* q1 = q0 + HW;
    const float* q2 = q1 + HW;

    // --- residual tile with reflect halo: 70*70 = 4900 = 19*256 + 36 ---
    const int y0 = by * TS - PAD;
    const int x0 = bx * TS - PAD;
#pragma unroll 4
    for (int it = 0; it < 19; ++it) {
        const int i  = tid + it * TPB;
        const int ly = i / TILE;
        const int lx = i - ly * TILE;
        int gy = y0 + ly;
        int gx = x0 + lx;
        gy = (gy < 0) ? -gy : ((gy >= H_DIM) ? (2 * H_DIM - 2 - gy) : gy);
        gx = (gx < 0) ? -gx : ((gx >= W_DIM) ? (2 * W_DIM - 2 - gx) : gx);
        const int off = gy * W_DIM + gx;
        tile[ly * TSTRIDE + lx] = fabsf(q0[off] - p0[off])
                                + fabsf(q1[off] - p1[off])
                                + fabsf(q2[off] - p2[off]);
    }
    if (tid < 36) {
        const int i  = tid + 19 * TPB;
        const int ly = i / TILE;
        const int lx = i - ly * TILE;
        int gy = y0 + ly;
        int gx = x0 + lx;
        gy = (gy < 0) ? -gy : ((gy >= H_DIM) ? (2 * H_DIM - 2 - gy) : gy);
        gx = (gx < 0) ? -gx : ((gx >= W_DIM) ? (2 * W_DIM - 2 - gx) : gx);
        const int off = gy * W_DIM + gx;
        tile[ly * TSTRIDE + lx] = fabsf(q0[off] - p0[off])
                                + fabsf(q1[off] - p1[off])
                                + fabsf(q2[off] - p2[off]);
    }
    __syncthreads();

    // --- 16 vertically-adjacent output pixels per thread ---
    const int tx  = tid & 63;              // output column 0..63
    const int ty0 = (tid >> 6) << 4;       // output rows ty0..ty0+15

    // ring buffer of per-row horizontal sums over the 7-wide window
    float rS[KS], rSS[KS];
    float S = 0.f, SS = 0.f;
#pragma unroll
    for (int dy = 0; dy < KS; ++dy) {
        float s = 0.f, ss = 0.f;
#pragma unroll
        for (int j = 0; j < KS; ++j) {
            const float v = tile[(ty0 + dy) * TSTRIDE + tx + j];
            s  += v;
            ss += v * v;
        }
        rS[dy] = s; rSS[dy] = ss;
        S += s; SS += ss;
    }

    float acc_r = 0.f, acc_r2 = 0.f, acc_c = 0.f;

#pragma unroll
    for (int k = 0; k < 16; ++k) {
        if (k > 0) {
            // slide down one row: add row ty0+6+k, drop oldest ring slot
            float s = 0.f, ss = 0.f;
#pragma unroll
            for (int j = 0; j < KS; ++j) {
                const float v = tile[(ty0 + 6 + k) * TSTRIDE + tx + j];
                s  += v;
                ss += v * v;
            }
            const int slot = (k - 1) % KS;   // compile-time after unroll
            S  += s  - rS[slot];
            SS += ss - rSS[slot];
            rS[slot] = s; rSS[slot] = ss;
        }
        const float pix_var = (SS - S * S * (1.0f / 49.0f)) * (1.0f / 48.0f);
        const float center  = tile[(ty0 + 3 + k) * TSTRIDE + tx + 3];

        acc_r  += center;
        acc_r2 += center * center;
        acc_c  += pix_var * center;
    }

    // --- block reduce 3 floats (wave shuffle -> LDS -> thread 0) ---
#pragma unroll
    for (int off = 32; off > 0; off >>= 1) {
        acc_r  += __shfl_down(acc_r,  off);
        acc_r2 += __shfl_down(acc_r2, off);
        acc_c  += __shfl_down(acc_c,  off);
    }
    __shared__ float sh_r[4], sh_r2[4], sh_c[4];
    const int lane = tid & 63;
    const int wave = tid >> 6;
    if (lane == 0) { sh_r[wave] = acc_r; sh_r2[wave] = acc_r2; sh_c[wave] = acc_c; }
    __syncthreads();
    if (tid == 0) {
        pr [bid] = sh_r [0] + sh_r [1] + sh_r [2] + sh_r [3];
        pr2[bid] = sh_r2[0] + sh_r2[1] + sh_r2[2] + sh_r2[3];
        pc [bid] = sh_c [0] + sh_c [1] + sh_c [2] + sh_c [3];
    }
}

// ---------------------------------------------------------------------------
// Finalize: wave w reduces image w's 64 partials in double; lane 0 applies
// pw_n = pvar^0.2; thread 0 sums the 16 images and writes the scalar.
// ---------------------------------------------------------------------------
__global__ void k_final(const float* __restrict__ pr,
                        const float* __restrict__ pr2,
                        const float* __restrict__ pc,
                        float* __restrict__ out) {
    __shared__ double sh[N_IMG];
    const int tid  = threadIdx.x;       // 1024 threads = 16 waves
    const int w    = tid >> 6;          // image index
    const int lane = tid & 63;

    double R = 0.0, R2 = 0.0, Cs = 0.0;
    if (lane < TILES_PER_IMG) {
        const int idx = w * TILES_PER_IMG + lane;
        R  = (double)pr[idx];
        R2 = (double)pr2[idx];
        Cs = (double)pc[idx];
    }
#pragma unroll
    for (int off = 32; off > 0; off >>= 1) {
        R  += __shfl_down(R,  off);
        R2 += __shfl_down(R2, off);
        Cs += __shfl_down(Cs, off);
    }
    if (lane == 0) {
        const double pvar = (R2 - R * R / (double)HW) / (double)(HW - 1);
        sh[w] = pow(pvar, 0.2) * Cs;
    }
    __syncthreads();
    if (tid == 0) {
        double s = 0.0;
        for (int i = 0; i < N_IMG; ++i) s += sh[i];
        out[0] = (float)(s / ((double)N_IMG * C_CH * HW));
    }
}

extern "C" void kernel_launch(void* const* d_in, const int* in_sizes, int n_in,
                              void* d_out, int out_size, void* d_ws, size_t ws_size,
                              hipStream_t stream) {
    const float* pred = (const float*)d_in[0];
    const float* targ = (const float*)d_in[1];

    float* pr  = (float*)d_ws;
    float* pr2 = pr  + NBLOCKS;
    float* pc  = pr2 + NBLOCKS;
    float* out = (float*)d_out;

    k_fused<<<NBLOCKS, TPB, 0, stream>>>(pred, targ, pr, pr2, pc);
    k_final<<<1, 1024, 0, stream>>>(pr, pr2, pc, out);
}